// Round 9
// baseline (87.533 us; speedup 1.0000x reference)
//
#include <hip/hip_runtime.h>
#include <hip/hip_bf16.h>

#define BDIM 4096
#define DDIM 512
#define TS 64                       // wave tile (rows == cols)
#define NT (BDIM / TS)              // 64 tiles per dim
#define NTRI (NT * (NT + 1) / 2)    // 2080 triangle wave-tiles
#define NKT (DDIM / 32)             // 16 k-steps of 32

typedef __bf16 bf16x8 __attribute__((ext_vector_type(8)));
typedef float f32x4 __attribute__((ext_vector_type(4)));
typedef unsigned short ushort_t;

__device__ inline ushort_t f2bf(float f) {
  __hip_bfloat16 h = __float2bfloat16(f);
  return *reinterpret_cast<ushort_t*>(&h);
}

// order-preserving float <-> uint mapping (monotonic) for atomic min/max
__device__ inline unsigned int enc_f32(float x) {
  unsigned int u = __float_as_uint(x);
  return (u & 0x80000000u) ? ~u : (u | 0x80000000u);
}
__device__ inline float dec_f32(unsigned int e) {
  unsigned int u = (e & 0x80000000u) ? (e ^ 0x80000000u) : ~e;
  return __uint_as_float(u);
}

// --- kernel 1: L2-normalize rows; emit E in MFMA-fragment-blocked layout ---
// E_blk elem addr: (rowblk*64 + kc)*128 + inrow*8 + kelem
//   rowblk = row>>4, inrow = row&15, kc = k>>3, kelem = k&7  (bf16 elems)
// A 16-row x 8-k fragment-block = 256 B contiguous; a wave's 4 consecutive
// kc blocks = 1 KB contiguous -> one coalesced dwordx4 frag load in gemm.
__global__ __launch_bounds__(256) void norm_kernel(const float* __restrict__ x,
                                                   ushort_t* __restrict__ e,
                                                   unsigned int* __restrict__ minpos_e,
                                                   unsigned int* __restrict__ maxneg_e,
                                                   unsigned int* __restrict__ done_ctr) {
  if (blockIdx.x == 0) {  // init shared state (stream order: before gemm)
    const unsigned int init_min = enc_f32(1e30f);
    const unsigned int init_max = enc_f32(-1e30f);
    for (int i = threadIdx.x; i < BDIM; i += 256) {
      minpos_e[i] = init_min;
      maxneg_e[i] = init_max;
    }
    if (threadIdx.x == 0) done_ctr[0] = 0u;
  }
  const int row  = blockIdx.x * 4 + (threadIdx.x >> 6);
  const int lane = threadIdx.x & 63;
  const float4* xr = reinterpret_cast<const float4*>(x + (size_t)row * DDIM);
  float4 v0 = xr[lane];          // k = lane*4 .. +3
  float4 v1 = xr[lane + 64];     // k = 256 + lane*4 .. +3
  float ss = v0.x*v0.x + v0.y*v0.y + v0.z*v0.z + v0.w*v0.w
           + v1.x*v1.x + v1.y*v1.y + v1.z*v1.z + v1.w*v1.w;
#pragma unroll
  for (int off = 32; off >= 1; off >>= 1) ss += __shfl_xor(ss, off);
  const float inv = 1.0f / fmaxf(sqrtf(ss), 1e-12f);

  ushort4 p0, p1;
  p0.x = f2bf(v0.x * inv); p0.y = f2bf(v0.y * inv);
  p0.z = f2bf(v0.z * inv); p0.w = f2bf(v0.w * inv);
  p1.x = f2bf(v1.x * inv); p1.y = f2bf(v1.y * inv);
  p1.z = f2bf(v1.z * inv); p1.w = f2bf(v1.w * inv);

  const int rb = row >> 4, ir = row & 15;
  const int kc = lane >> 1;                 // kchunk within first half
  const int ke = (lane & 1) * 4;            // kelem 0 or 4
  ushort_t* base = e + ((size_t)rb * 64) * 128 + ir * 8 + ke;
  *reinterpret_cast<ushort4*>(base + (size_t)kc * 128)        = p0;
  *reinterpret_cast<ushort4*>(base + (size_t)(32 + kc) * 128) = p1;
}

// --- kernel 2: LDS-free triangle GEMM; frags streamed from L2; fused reduce --
// One wave (64 threads) per 64x64 triangle tile (i <= j). No barriers.
__global__ __launch_bounds__(64, 2) void gemm_reduce_kernel(
    const ushort_t* __restrict__ e, const int* __restrict__ labels,
    unsigned int* __restrict__ minpos_e, unsigned int* __restrict__ maxneg_e,
    unsigned int* __restrict__ done_ctr, float* __restrict__ out) {
  const int lane = threadIdx.x;
  const int l15  = lane & 15;
  const int g    = lane >> 4;     // 0..3

  // XCD swizzle (2080 = 8*260, exact) then triangle decode: off(i)=64i-i(i-1)/2
  const int bid = blockIdx.x;
  const int t   = (bid & 7) * (NTRI / 8) + (bid >> 3);
  int I = (int)(64.5f - sqrtf(4160.25f - 2.0f * (float)t));
  if (I < 0) I = 0;
  if (I > NT - 1) I = NT - 1;
  while (I < NT - 1 && 64 * (I + 1) - ((I + 1) * I) / 2 <= t) ++I;
  while (I > 0 && 64 * I - (I * (I - 1)) / 2 > t) --I;
  const int J = I + (t - (64 * I - (I * (I - 1)) / 2));

  // fragment base pointers (elems); m stride = 64*128, kt stride = 4*128
  const ushort_t* baseA = e + ((size_t)(4 * I) * 64) * 128 + lane * 8;
  const ushort_t* baseB = e + ((size_t)(4 * J) * 64) * 128 + lane * 8;

  f32x4 acc[4][4];
#pragma unroll
  for (int m = 0; m < 4; ++m)
#pragma unroll
    for (int n = 0; n < 4; ++n) acc[m][n] = (f32x4){0.f, 0.f, 0.f, 0.f};

#define LOADF(av, bv, kt)                                                      \
  do {                                                                         \
    _Pragma("unroll")                                                          \
    for (int m = 0; m < 4; ++m) {                                              \
      av[m] = *reinterpret_cast<const bf16x8*>(baseA + m * 8192 + (kt) * 512); \
      bv[m] = *reinterpret_cast<const bf16x8*>(baseB + m * 8192 + (kt) * 512); \
    }                                                                          \
  } while (0)

#define MF(av, bv)                                                             \
  do {                                                                         \
    _Pragma("unroll")                                                          \
    for (int m = 0; m < 4; ++m)                                                \
      _Pragma("unroll")                                                        \
      for (int n = 0; n < 4; ++n)                                              \
        acc[m][n] = __builtin_amdgcn_mfma_f32_16x16x32_bf16(av[m], bv[n],      \
                                                            acc[m][n], 0, 0, 0);\
  } while (0)

  bf16x8 aA[4], bA[4], aB[4], bB[4];
  LOADF(aA, bA, 0);
  LOADF(aB, bB, 1);
#pragma unroll
  for (int kt = 0; kt < NKT; kt += 2) {
    MF(aA, bA);
    if (kt + 2 < NKT) LOADF(aA, bA, kt + 2);
    MF(aB, bB);
    if (kt + 3 < NKT) LOADF(aB, bB, kt + 3);
  }
#undef LOADF
#undef MF

  // labels via coalesced load + shuffle
  const int lab_i = labels[I * TS + lane];
  const int lab_j = labels[J * TS + lane];

  // ---- dual-direction masked min/max epilogue ----------------------------
  // C/D 16x16 layout: col = l15, row = g*4 + r.
  float cmp[4], cmx[4];
  int lj[4], gj[4];
#pragma unroll
  for (int n = 0; n < 4; ++n) {
    cmp[n] = 1e30f; cmx[n] = -1e30f;
    gj[n]  = J * TS + n * 16 + l15;
    lj[n]  = __shfl(lab_j, n * 16 + l15);
  }
  float rmp[4][4], rmx[4][4];
#pragma unroll
  for (int m = 0; m < 4; ++m)
#pragma unroll
    for (int r = 0; r < 4; ++r) { rmp[m][r] = 1e30f; rmx[m][r] = -1e30f; }

#pragma unroll
  for (int m = 0; m < 4; ++m) {
#pragma unroll
    for (int r = 0; r < 4; ++r) {
      const int gi = I * TS + m * 16 + g * 4 + r;
      const int li = __shfl(lab_i, m * 16 + g * 4 + r);
#pragma unroll
      for (int n = 0; n < 4; ++n) {
        const float v = acc[m][n][r];
        if (li == lj[n]) {
          if (gi != gj[n]) {
            rmp[m][r] = fminf(rmp[m][r], v);
            cmp[n]    = fminf(cmp[n], v);
          }
        } else {
          rmx[m][r] = fmaxf(rmx[m][r], v);
          cmx[n]    = fmaxf(cmx[n], v);
        }
      }
    }
  }

  // col-dir reduce across g lanes (xor 16, 32)
#pragma unroll
  for (int off = 16; off <= 32; off <<= 1) {
#pragma unroll
    for (int n = 0; n < 4; ++n) {
      cmp[n] = fminf(cmp[n], __shfl_xor(cmp[n], off));
      cmx[n] = fmaxf(cmx[n], __shfl_xor(cmx[n], off));
    }
  }
  // row-dir reduce across l15 lanes (xor 1,2,4,8)
#pragma unroll
  for (int off = 1; off < 16; off <<= 1) {
#pragma unroll
    for (int m = 0; m < 4; ++m)
#pragma unroll
      for (int r = 0; r < 4; ++r) {
        rmp[m][r] = fminf(rmp[m][r], __shfl_xor(rmp[m][r], off));
        rmx[m][r] = fmaxf(rmx[m][r], __shfl_xor(rmx[m][r], off));
      }
  }

  if (g == 0) {
#pragma unroll
    for (int n = 0; n < 4; ++n) {
      if (cmp[n] < 1e29f)  atomicMin(&minpos_e[gj[n]], enc_f32(cmp[n]));
      if (cmx[n] > -1e29f) atomicMax(&maxneg_e[gj[n]], enc_f32(cmx[n]));
    }
  }
  if (l15 == 0) {
#pragma unroll
    for (int m = 0; m < 4; ++m)
#pragma unroll
      for (int r = 0; r < 4; ++r) {
        const int gi = I * TS + m * 16 + g * 4 + r;
        if (rmp[m][r] < 1e29f)  atomicMin(&minpos_e[gi], enc_f32(rmp[m][r]));
        if (rmx[m][r] > -1e29f) atomicMax(&maxneg_e[gi], enc_f32(rmx[m][r]));
      }
  }

  // ---- last-wave-done finalize -------------------------------------------
  __threadfence();   // release: our atomics globally visible before bump
  unsigned int rank = 0;
  if (lane == 0) rank = atomicAdd(done_ctr, 1u);
  rank = __shfl(rank, 0);
  if (rank == NTRI - 1) {
    __threadfence(); // acquire
    float sum = 0.f;
    int cnt = 0;
    for (int row = lane; row < BDIM; row += 64) {
      const unsigned int ump = __hip_atomic_load(&minpos_e[row], __ATOMIC_RELAXED,
                                                 __HIP_MEMORY_SCOPE_AGENT);
      const unsigned int umn = __hip_atomic_load(&maxneg_e[row], __ATOMIC_RELAXED,
                                                 __HIP_MEMORY_SCOPE_AGENT);
      const float mp = dec_f32(ump);
      const float mn = dec_f32(umn);
      if (mp < 1e29f && mn > -1e29f) {
        // hp - hn + margin = (1-mp) - (1-mn) + 0.2 = mn - mp + 0.2
        sum += fmaxf(0.f, mn - mp + 0.2f);
        cnt += 1;
      }
    }
#pragma unroll
    for (int off = 32; off >= 1; off >>= 1) {
      sum += __shfl_xor(sum, off);
      cnt += __shfl_xor(cnt, off);
    }
    if (lane == 0) out[0] = sum / (float)(cnt > 0 ? cnt : 1);
  }
}

extern "C" void kernel_launch(void* const* d_in, const int* in_sizes, int n_in,
                              void* d_out, int out_size, void* d_ws, size_t ws_size,
                              hipStream_t stream) {
  const float* x      = (const float*)d_in[0];
  const int*   labels = (const int*)d_in[1];
  float* out = (float*)d_out;

  char* ws = (char*)d_ws;
  ushort_t* e            = (ushort_t*)ws;                            // 4 MB E_blk
  unsigned int* minpos_e = (unsigned int*)(ws + (size_t)BDIM * DDIM * 2);
  unsigned int* maxneg_e = minpos_e + BDIM;
  unsigned int* done_ctr = maxneg_e + BDIM;

  norm_kernel<<<BDIM / 4, 256, 0, stream>>>(x, e, minpos_e, maxneg_e, done_ctr);
  gemm_reduce_kernel<<<NTRI, 64, 0, stream>>>(e, labels, minpos_e, maxneg_e,
                                              done_ctr, out);
}